// Round 4
// baseline (73.070 us; speedup 1.0000x reference)
//
#include <hip/hip_runtime.h>
#include <stdint.h>

#define V_CONST 50257
#define NMASK ((V_CONST + 31) / 32)
#define KTOP 50
#define NQ 4
#define Q4 12565              // ceil(V/4); last quarter = 12562
#define CAP_Q 512
#define CAND_CAP 2048
#define THR_SCREEN 13.0f
#define C_TEMP 1.25f
#define C_PEN ((float)(1.25 / 1.2))
#define K1_THREADS 256
#define K2_THREADS 256
#define THREEFRY_PARTITIONABLE 1

__device__ __forceinline__ void tf_round(uint32_t &x0, uint32_t &x1, int r) {
  x0 += x1;
  x1 = (x1 << r) | (x1 >> (32 - r));
  x1 ^= x0;
}

// Threefry-2x32, 20 rounds, key = (0, 42)  [jax.random.key(42)]
__device__ __forceinline__ uint2 threefry_k_0_42(uint32_t x0, uint32_t x1) {
  const uint32_t ks0 = 0u;
  const uint32_t ks1 = 42u;
  const uint32_t ks2 = 0x1BD11BDAu ^ 0u ^ 42u;
  x0 += ks0; x1 += ks1;
  tf_round(x0, x1, 13); tf_round(x0, x1, 15); tf_round(x0, x1, 26); tf_round(x0, x1, 6);
  x0 += ks1; x1 += ks2 + 1u;
  tf_round(x0, x1, 17); tf_round(x0, x1, 29); tf_round(x0, x1, 16); tf_round(x0, x1, 24);
  x0 += ks2; x1 += ks0 + 2u;
  tf_round(x0, x1, 13); tf_round(x0, x1, 15); tf_round(x0, x1, 26); tf_round(x0, x1, 6);
  x0 += ks0; x1 += ks1 + 3u;
  tf_round(x0, x1, 17); tf_round(x0, x1, 29); tf_round(x0, x1, 16); tf_round(x0, x1, 24);
  x0 += ks1; x1 += ks2 + 4u;
  tf_round(x0, x1, 13); tf_round(x0, x1, 15); tf_round(x0, x1, 26); tf_round(x0, x1, 6);
  x0 += ks2; x1 += ks0 + 5u;
  uint2 r; r.x = x0; r.y = x1; return r;
}

__device__ __forceinline__ float gumbel_at(uint32_t p, uint32_t half_total) {
  uint32_t bits;
#if THREEFRY_PARTITIONABLE
  uint2 o = threefry_k_0_42(0u, p);
  bits = o.x ^ o.y;
#else
  if (p < half_total) {
    uint2 o = threefry_k_0_42(p, p + half_total);
    bits = o.x;
  } else {
    uint2 o = threefry_k_0_42(p - half_total, p);
    bits = o.y;
  }
#endif
  uint32_t ub = (bits >> 9) | 0x3F800000u;
  float u = __uint_as_float(ub) - 1.0f;
  u = u + 1.17549435e-38f;
  u = fmaxf(1.17549435e-38f, u);
  return -logf(-logf(u));
}

__device__ __forceinline__ uint32_t f2u_desc(float f) {
  uint32_t b = __float_as_uint(f);
  return (b & 0x80000000u) ? ~b : (b | 0x80000000u);
}
__device__ __forceinline__ float u2f(uint32_t u) {
  uint32_t b = (u & 0x80000000u) ? (u & 0x7FFFFFFFu) : ~u;
  return __uint_as_float(b);
}

// ================= K1: screen + zero-fill (4 blocks per row) =================
__global__ __launch_bounds__(K1_THREADS) void screen_kernel(
    const float* __restrict__ logits, const int* __restrict__ generated,
    float* __restrict__ out, uint2* __restrict__ pairs, int* __restrict__ counts,
    int B, int T) {
  const int bid = blockIdx.x;
  const int row = bid >> 2, q = bid & 3;
  const int tid = threadIdx.x;
  const int vlo = q * Q4;
  const int vhi = min(V_CONST, vlo + Q4);
  const int len = vhi - vlo;
  const int w0 = vlo >> 5;
  const int nw = ((vhi + 31) >> 5) - w0;

  __shared__ uint32_t qmask[(Q4 >> 5) + 2];
  __shared__ int s_cnt;

  for (int i = tid; i < nw; i += K1_THREADS) qmask[i] = 0u;
  if (tid == 0) s_cnt = 0;
  __syncthreads();

  // quarter present-mask (LDS-only barrier: no global stores in flight yet)
  const int* grow = generated + (size_t)row * T;
  for (int i = tid; i < T; i += K1_THREADS) {
    int tok = grow[i];
    if (tok >= vlo && tok < vhi)
      atomicOr(&qmask[(tok >> 5) - w0], 1u << (tok & 31));
  }
  __syncthreads();

  // issue this quarter's probs zero-fill; drains under the screen pass
  {
    size_t e0 = (size_t)B + (size_t)row * V_CONST + vlo;
    size_t e1 = e0 + len;
    size_t a0 = (e0 + 3) & ~(size_t)3;
    size_t a1 = e1 & ~(size_t)3;
    for (size_t e = e0 + tid; e < a0; e += K1_THREADS) out[e] = 0.f;
    float4* o4 = (float4*)(out + a0);
    size_t n4 = (a1 - a0) >> 2;
    float4 z4 = make_float4(0.f, 0.f, 0.f, 0.f);
    for (size_t i = tid; i < n4; i += K1_THREADS) o4[i] = z4;
    for (size_t e = a1 + tid; e < e1; e += K1_THREADS) out[e] = 0.f;
  }

  // screen this quarter; store (exact_ukey, idx) for passers
  const float* lrow = logits + (size_t)row * V_CONST;
  const int aoff = (4 - ((row + q) & 3)) & 3;  // V%4==1, Q4%4==1
  const int body4 = (len - aoff) >> 2;
  const int tailn = (len - aoff) & 3;
  const float4* arow4 = (const float4*)(lrow + vlo + aoff);
  uint2* mypairs = pairs + (size_t)bid * CAP_Q;

#define SCREEN1(xv, vv) do {                                          \
    int v_ = (vv); float x_ = (xv);                                   \
    uint32_t pres_ = (qmask[(v_ >> 5) - w0] >> (v_ & 31)) & 1u;       \
    float m_ = pres_ ? C_PEN : C_TEMP;                                \
    if (x_ * m_ >= THR_SCREEN) {                                      \
      float xe_ = x_ / 0.8f; if (pres_) xe_ = xe_ / 1.2f;             \
      int p_ = atomicAdd(&s_cnt, 1);                                  \
      if (p_ < CAP_Q) mypairs[p_] = make_uint2(f2u_desc(xe_), (uint32_t)v_); \
    } } while (0)

  for (int t = tid; t < body4; t += K1_THREADS) {
    float4 r = arow4[t];
    int v0 = vlo + aoff + (t << 2);
    SCREEN1(r.x, v0 + 0);
    SCREEN1(r.y, v0 + 1);
    SCREEN1(r.z, v0 + 2);
    SCREEN1(r.w, v0 + 3);
  }
  if (tid < aoff + tailn) {
    int v = (tid < aoff) ? (vlo + tid) : (vhi - tailn + (tid - aoff));
    SCREEN1(lrow[v], v);
  }
#undef SCREEN1
  __syncthreads();
  if (tid == 0) counts[bid] = s_cnt;
}

// ================= K2: gather + sort + top-k/top-p + sample ==================
__global__ __launch_bounds__(K2_THREADS) void sample_kernel2(
    const float* __restrict__ logits, const int* __restrict__ generated,
    float* __restrict__ out, const uint2* __restrict__ pairs,
    const int* __restrict__ counts, int B, int T) {
  const int b = blockIdx.x;
  const int tid = threadIdx.x;

  __shared__ uint32_t cu[CAND_CAP];
  __shared__ int      cidx[CAND_CAP];
  __shared__ uint32_t su[CAND_CAP];
  __shared__ int      sidx[CAND_CAP];
  __shared__ float    eg[CAND_CAP];
  __shared__ float    gg[CAND_CAP];
  __shared__ uint32_t mask[NMASK];        // fallback only
  __shared__ int s_ncand, s_nsurv, s_rlast;
  __shared__ float s_z2;

  int cq[NQ];
  int total = 0;
  bool ovf = false;
  #pragma unroll
  for (int q = 0; q < NQ; q++) {
    cq[q] = counts[b * NQ + q];
    if (cq[q] > CAP_Q) ovf = true;
    total += cq[q];
  }
  bool fast = (!ovf) && total >= KTOP && total <= CAND_CAP;
  int n = 0;
  bool ok = false;

  if (fast) {
    int off = 0;
    #pragma unroll
    for (int q = 0; q < NQ; q++) {
      const uint2* pp = pairs + (size_t)(b * NQ + q) * CAP_Q;
      for (int i = tid; i < cq[q]; i += K2_THREADS) {
        uint2 pr = pp[i];
        cu[off + i] = pr.x; cidx[off + i] = (int)pr.y;
      }
      off += cq[q];
    }
    n = total;
    __syncthreads();
    // stable rank sort (descending, ties by smaller index)
    for (int i = tid; i < n; i += K2_THREADS) {
      uint32_t ui = cu[i]; int ii = cidx[i];
      int rank = 0;
      for (int j = 0; j < n; j++) {
        uint32_t uj = cu[j];
        rank += ((uj > ui) || (uj == ui && cidx[j] < ii)) ? 1 : 0;
      }
      su[rank] = ui; sidx[rank] = ii;
    }
    __syncthreads();
    // certificate: non-passers have exact key < f2u(THR)+~4 ulp
    if (su[KTOP - 1] >= f2u_desc(THR_SCREEN) + 64u) ok = true;
  }

  if (!ok) {
    // ---- robust fallback: full re-scan with bisection (never taken here) ----
    for (int i = tid; i < NMASK; i += K2_THREADS) mask[i] = 0u;
    __syncthreads();
    const int* grow = generated + (size_t)b * T;
    for (int i = tid; i < T; i += K2_THREADS) {
      int tok = grow[i];
      atomicOr(&mask[tok >> 5], 1u << (tok & 31));
    }
    __syncthreads();
    const float* lrow = logits + (size_t)b * V_CONST;
    const int aoff = (4 - (b & 3)) & 3;
    const int tailn = (V_CONST - aoff) & 3;
    const int body4 = (V_CONST - aoff) >> 2;
    const float4* arow4 = (const float4*)(lrow + aoff);
    float thr = THR_SCREEN;
    uint32_t ulo_ = 0u, uhi_ = 0xFFFFFFFFu;
    n = 0;
    for (int attempt = 0; attempt < 64; ++attempt) {
      __syncthreads();
      if (tid == 0) s_ncand = 0;
      __syncthreads();
      for (int t = tid; t < body4; t += K2_THREADS) {
        float4 r = arow4[t];
        int v0 = aoff + (t << 2);
        uint32_t w = (mask[v0 >> 5] >> (v0 & 31)) & 0xFu;
        float m0 = (w & 1u) ? C_PEN : C_TEMP;
        float m1 = (w & 2u) ? C_PEN : C_TEMP;
        float m2 = (w & 4u) ? C_PEN : C_TEMP;
        float m3 = (w & 8u) ? C_PEN : C_TEMP;
        if (r.x * m0 >= thr) { int p = atomicAdd(&s_ncand, 1); if (p < CAND_CAP) { cu[p] = __float_as_uint(r.x); cidx[p] = v0; } }
        if (r.y * m1 >= thr) { int p = atomicAdd(&s_ncand, 1); if (p < CAND_CAP) { cu[p] = __float_as_uint(r.y); cidx[p] = v0 + 1; } }
        if (r.z * m2 >= thr) { int p = atomicAdd(&s_ncand, 1); if (p < CAND_CAP) { cu[p] = __float_as_uint(r.z); cidx[p] = v0 + 2; } }
        if (r.w * m3 >= thr) { int p = atomicAdd(&s_ncand, 1); if (p < CAND_CAP) { cu[p] = __float_as_uint(r.w); cidx[p] = v0 + 3; } }
      }
      if (tid < aoff + tailn) {
        int v = (tid < aoff) ? tid : (V_CONST - tailn) + (tid - aoff);
        float x = lrow[v];
        float m = ((mask[v >> 5] >> (v & 31)) & 1u) ? C_PEN : C_TEMP;
        if (x * m >= thr) { int p = atomicAdd(&s_ncand, 1); if (p < CAND_CAP) { cu[p] = __float_as_uint(x); cidx[p] = v; } }
      }
      __syncthreads();
      const int tot = s_ncand;
      n = (tot < CAND_CAP) ? tot : CAND_CAP;
      const bool window = (tot >= KTOP && tot <= CAND_CAP);
      const bool last = (attempt == 63);
      if (window || last) {
        if (n > 0) {
          for (int i = tid; i < n; i += K2_THREADS) {
            float x = __uint_as_float(cu[i]);
            int v = cidx[i];
            float xe = x / 0.8f;
            if ((mask[v >> 5] >> (v & 31)) & 1u) xe = xe / 1.2f;
            cu[i] = f2u_desc(xe);
          }
          __syncthreads();
          for (int i = tid; i < n; i += K2_THREADS) {
            uint32_t ui = cu[i]; int ii = cidx[i];
            int rank = 0;
            for (int j = 0; j < n; j++) {
              uint32_t uj = cu[j];
              rank += ((uj > ui) || (uj == ui && cidx[j] < ii)) ? 1 : 0;
            }
            su[rank] = ui; sidx[rank] = ii;
          }
          __syncthreads();
        }
        if (window) {
          if (su[KTOP - 1] >= f2u_desc(thr) + 64u) break;
          if (last) break;
          thr = u2f(su[KTOP - 1] >= 96u ? su[KTOP - 1] - 96u : 0u);
        } else break;
      } else if (tot < KTOP) {
        uhi_ = f2u_desc(thr);
        if (attempt == 0) thr = 11.0f;
        else {
          uint32_t mid = ulo_ + (uhi_ - ulo_) / 2u;
          if (mid >= uhi_) mid = uhi_ - 1u;
          thr = u2f(mid);
        }
      } else {
        ulo_ = f2u_desc(thr);
        uint32_t mid = ulo_ + (uhi_ - ulo_) / 2u;
        if (mid <= ulo_) mid = ulo_ + 1u;
        thr = u2f(mid);
      }
    }
  }

  if (n == 0) { if (tid == 0) out[b] = 0.f; return; }

  // ---- top-k survivors (>= kth incl. ties) ----
  if (tid == 0) {
    int kpos = (n < KTOP) ? (n - 1) : (KTOP - 1);
    uint32_t kth = su[kpos];
    int ns = kpos + 1;
    while (ns < n && su[ns] == kth) ns++;
    s_nsurv = ns;
  }
  __syncthreads();
  const int nsurv = s_nsurv;
  const float s0 = u2f(su[0]);
  const uint32_t half_total = (uint32_t)((size_t)256 * V_CONST / 2);

  for (int r = tid; r < nsurv; r += K2_THREADS) {
    float f = u2f(su[r]);
    eg[r] = expf(f - s0);
    gg[r] = gumbel_at((uint32_t)(b * V_CONST + sidx[r]), half_total);
  }
  __syncthreads();

  if (tid == 0) {
    float zall = 0.f;
    for (int r = 0; r < nsurv; r++) zall += eg[r];
    float cum = 0.f;
    int rlast = 0;
    for (int r = 0; r < nsurv; r++) {
      cum += eg[r] / zall;
      if (r == 0 || cum <= 0.9f) rlast = r;
      else break;
    }
    float z2 = 0.f;
    for (int r = 0; r <= rlast; r++) z2 += eg[r];
    float best = -3.402823466e38f; int besti = V_CONST;
    for (int r = 0; r <= rlast; r++) {
      float sc = u2f(su[r]) + gg[r];
      int idx = sidx[r];
      if (sc > best || (sc == best && idx < besti)) { best = sc; besti = idx; }
    }
    out[b] = (float)besti;
    s_rlast = rlast; s_z2 = z2;
  }
  __syncthreads();
  const int rlast = s_rlast;
  const float z2 = s_z2;

  // scatter kept probs (row zeroed by K1; kernel boundary ordered it)
  float* prow = out + B + (size_t)b * V_CONST;
  for (int r = tid; r <= rlast; r += K2_THREADS) {
    prow[sidx[r]] = eg[r] / z2;
  }
}

extern "C" void kernel_launch(void* const* d_in, const int* in_sizes, int n_in,
                              void* d_out, int out_size, void* d_ws, size_t ws_size,
                              hipStream_t stream) {
  const float* logits = (const float*)d_in[0];
  const int* generated = (const int*)d_in[1];
  float* out = (float*)d_out;
  const int B = in_sizes[0] / V_CONST;
  const int T = in_sizes[1] / B;
  int* counts = (int*)d_ws;
  uint2* pairs = (uint2*)((char*)d_ws + 4096);
  hipLaunchKernelGGL(screen_kernel, dim3(B * NQ), dim3(K1_THREADS), 0, stream,
                     logits, generated, out, pairs, counts, B, T);
  hipLaunchKernelGGL(sample_kernel2, dim3(B), dim3(K2_THREADS), 0, stream,
                     logits, generated, out, pairs, counts, B, T);
}

// Round 5
// 32.756 us; speedup vs baseline: 2.2307x; 2.2307x over previous
//
#include <hip/hip_runtime.h>
#include <stdint.h>

#define V_CONST 50257
#define NMASK ((V_CONST + 31) / 32)
#define KTOP 50
#define CAND_CAP 1024
#define NTHREADS 1024
#define THR_SCREEN 13.0f
#define C_TEMP 1.25f
#define C_PEN ((float)(1.25 / 1.2))
#define THREEFRY_PARTITIONABLE 1

__device__ __forceinline__ void tf_round(uint32_t &x0, uint32_t &x1, int r) {
  x0 += x1;
  x1 = (x1 << r) | (x1 >> (32 - r));
  x1 ^= x0;
}

// Threefry-2x32, 20 rounds, key = (0, 42)  [jax.random.key(42)]
__device__ __forceinline__ uint2 threefry_k_0_42(uint32_t x0, uint32_t x1) {
  const uint32_t ks0 = 0u;
  const uint32_t ks1 = 42u;
  const uint32_t ks2 = 0x1BD11BDAu ^ 0u ^ 42u;
  x0 += ks0; x1 += ks1;
  tf_round(x0, x1, 13); tf_round(x0, x1, 15); tf_round(x0, x1, 26); tf_round(x0, x1, 6);
  x0 += ks1; x1 += ks2 + 1u;
  tf_round(x0, x1, 17); tf_round(x0, x1, 29); tf_round(x0, x1, 16); tf_round(x0, x1, 24);
  x0 += ks2; x1 += ks0 + 2u;
  tf_round(x0, x1, 13); tf_round(x0, x1, 15); tf_round(x0, x1, 26); tf_round(x0, x1, 6);
  x0 += ks0; x1 += ks1 + 3u;
  tf_round(x0, x1, 17); tf_round(x0, x1, 29); tf_round(x0, x1, 16); tf_round(x0, x1, 24);
  x0 += ks1; x1 += ks2 + 4u;
  tf_round(x0, x1, 13); tf_round(x0, x1, 15); tf_round(x0, x1, 26); tf_round(x0, x1, 6);
  x0 += ks2; x1 += ks0 + 5u;
  uint2 r; r.x = x0; r.y = x1; return r;
}

__device__ __forceinline__ float gumbel_at(uint32_t p, uint32_t half_total) {
  uint32_t bits;
#if THREEFRY_PARTITIONABLE
  uint2 o = threefry_k_0_42(0u, p);
  bits = o.x ^ o.y;
#else
  if (p < half_total) {
    uint2 o = threefry_k_0_42(p, p + half_total);
    bits = o.x;
  } else {
    uint2 o = threefry_k_0_42(p - half_total, p);
    bits = o.y;
  }
#endif
  uint32_t ub = (bits >> 9) | 0x3F800000u;
  float u = __uint_as_float(ub) - 1.0f;
  u = u + 1.17549435e-38f;
  u = fmaxf(1.17549435e-38f, u);
  return -logf(-logf(u));
}

__device__ __forceinline__ uint32_t f2u_desc(float f) {
  uint32_t b = __float_as_uint(f);
  return (b & 0x80000000u) ? ~b : (b | 0x80000000u);
}
__device__ __forceinline__ float u2f(uint32_t u) {
  uint32_t b = (u & 0x80000000u) ? (u & 0x7FFFFFFFu) : ~u;
  return __uint_as_float(b);
}

__global__ __launch_bounds__(NTHREADS) void sample_kernel(
    const float* __restrict__ logits, const int* __restrict__ generated,
    float* __restrict__ out, int B, int T) {
  const int b = blockIdx.x;
  const int tid = threadIdx.x;

  __shared__ uint32_t mask[NMASK];
  __shared__ uint32_t cu[CAND_CAP];
  __shared__ int      cidx[CAND_CAP];
  __shared__ uint32_t su[CAND_CAP];
  __shared__ int      sidx[CAND_CAP];
  __shared__ float    eg[CAND_CAP];
  __shared__ float    gg[CAND_CAP];
  __shared__ int s_ncand, s_nsurv, s_rlast;
  __shared__ float s_z2;

  // ---- A: present-token bitmask (LDS only; barrier is cheap) ----
  for (int i = tid; i < NMASK; i += NTHREADS) mask[i] = 0u;
  if (tid == 0) s_ncand = 0;
  __syncthreads();
  const int* grow = generated + (size_t)b * T;
  for (int i = tid; i < T; i += NTHREADS) {
    int tok = grow[i];
    atomicOr(&mask[tok >> 5], 1u << (tok & 31));
  }
  __syncthreads();

  // ---- B: fused screen + exact-key collect + probs zero-fill ----
  // probs row (out + B + b*V) and logits row share alignment: b*V = b mod 4, B = 0 mod 4
  const float* lrow = logits + (size_t)b * V_CONST;
  float* prow = out + B + (size_t)b * V_CONST;
  const int aoff = (4 - (b & 3)) & 3;
  const int tailn = (V_CONST - aoff) & 3;
  const int body4 = (V_CONST - aoff) >> 2;
  const float4* arow4 = (const float4*)(lrow + aoff);
  float4* orow4 = (float4*)(prow + aoff);
  const float4 z4 = make_float4(0.f, 0.f, 0.f, 0.f);

#define SCREEN1(xv, vv) do {                                          \
    int v_ = (vv); float x_ = (xv);                                   \
    uint32_t pres_ = (mask[v_ >> 5] >> (v_ & 31)) & 1u;               \
    float m_ = pres_ ? C_PEN : C_TEMP;                                \
    if (x_ * m_ >= THR_SCREEN) {                                      \
      float xe_ = x_ / 0.8f; if (pres_) xe_ = xe_ / 1.2f;             \
      int p_ = atomicAdd(&s_ncand, 1);                                \
      if (p_ < CAND_CAP) { cu[p_] = f2u_desc(xe_); cidx[p_] = v_; }   \
    } } while (0)

  for (int t = tid; t < body4; t += NTHREADS) {
    float4 r = arow4[t];
    orow4[t] = z4;                      // zero-fill rides along the read stream
    int v0 = aoff + (t << 2);
    SCREEN1(r.x, v0 + 0);
    SCREEN1(r.y, v0 + 1);
    SCREEN1(r.z, v0 + 2);
    SCREEN1(r.w, v0 + 3);
  }
  if (tid < aoff + tailn) {
    int v = (tid < aoff) ? tid : (V_CONST - tailn) + (tid - aoff);
    prow[v] = 0.f;
    SCREEN1(lrow[v], v);
  }
#undef SCREEN1
  __syncthreads();

  const int total = s_ncand;
  int n = (total < CAND_CAP) ? total : CAND_CAP;
  bool ok = false;

  if (total >= KTOP && total <= CAND_CAP) {
    // ---- C: stable rank sort (descending, ties by smaller index) ----
    for (int i = tid; i < n; i += NTHREADS) {
      uint32_t ui = cu[i]; int ii = cidx[i];
      int rank = 0;
      for (int j = 0; j < n; j++) {
        uint32_t uj = cu[j];
        rank += ((uj > ui) || (uj == ui && cidx[j] < ii)) ? 1 : 0;
      }
      su[rank] = ui; sidx[rank] = ii;
    }
    __syncthreads();   // residual zero-fill drain hides under the sort
    // certificate: non-passers have exact key < f2u(THR)+~4 ulp
    ok = (su[KTOP - 1] >= f2u_desc(THR_SCREEN) + 64u);
  } else {
    __syncthreads();
  }

  if (!ok) {
    // ---- robust fallback: bisection re-scan (never taken on this data) ----
    float thr = THR_SCREEN;
    uint32_t ulo_ = 0u, uhi_ = 0xFFFFFFFFu;
    n = 0;
    for (int attempt = 0; attempt < 64; ++attempt) {
      __syncthreads();
      if (tid == 0) s_ncand = 0;
      __syncthreads();
      for (int t = tid; t < body4; t += NTHREADS) {
        float4 r = arow4[t];
        int v0 = aoff + (t << 2);
        uint32_t w = (mask[v0 >> 5] >> (v0 & 31)) & 0xFu;
        float m0 = (w & 1u) ? C_PEN : C_TEMP;
        float m1 = (w & 2u) ? C_PEN : C_TEMP;
        float m2 = (w & 4u) ? C_PEN : C_TEMP;
        float m3 = (w & 8u) ? C_PEN : C_TEMP;
        if (r.x * m0 >= thr) { int p = atomicAdd(&s_ncand, 1); if (p < CAND_CAP) { cu[p] = __float_as_uint(r.x); cidx[p] = v0; } }
        if (r.y * m1 >= thr) { int p = atomicAdd(&s_ncand, 1); if (p < CAND_CAP) { cu[p] = __float_as_uint(r.y); cidx[p] = v0 + 1; } }
        if (r.z * m2 >= thr) { int p = atomicAdd(&s_ncand, 1); if (p < CAND_CAP) { cu[p] = __float_as_uint(r.z); cidx[p] = v0 + 2; } }
        if (r.w * m3 >= thr) { int p = atomicAdd(&s_ncand, 1); if (p < CAND_CAP) { cu[p] = __float_as_uint(r.w); cidx[p] = v0 + 3; } }
      }
      if (tid < aoff + tailn) {
        int v = (tid < aoff) ? tid : (V_CONST - tailn) + (tid - aoff);
        float x = lrow[v];
        float m = ((mask[v >> 5] >> (v & 31)) & 1u) ? C_PEN : C_TEMP;
        if (x * m >= thr) { int p = atomicAdd(&s_ncand, 1); if (p < CAND_CAP) { cu[p] = __float_as_uint(x); cidx[p] = v; } }
      }
      __syncthreads();
      const int tot = s_ncand;
      n = (tot < CAND_CAP) ? tot : CAND_CAP;
      const bool window = (tot >= KTOP && tot <= CAND_CAP);
      const bool last = (attempt == 63);
      if (window || last) {
        if (n > 0) {
          for (int i = tid; i < n; i += NTHREADS) {
            float x = __uint_as_float(cu[i]);
            int v = cidx[i];
            float xe = x / 0.8f;
            if ((mask[v >> 5] >> (v & 31)) & 1u) xe = xe / 1.2f;
            cu[i] = f2u_desc(xe);
          }
          __syncthreads();
          for (int i = tid; i < n; i += NTHREADS) {
            uint32_t ui = cu[i]; int ii = cidx[i];
            int rank = 0;
            for (int j = 0; j < n; j++) {
              uint32_t uj = cu[j];
              rank += ((uj > ui) || (uj == ui && cidx[j] < ii)) ? 1 : 0;
            }
            su[rank] = ui; sidx[rank] = ii;
          }
          __syncthreads();
        }
        if (window) {
          if (su[KTOP - 1] >= f2u_desc(thr) + 64u) break;
          if (last) break;
          thr = u2f(su[KTOP - 1] >= 96u ? su[KTOP - 1] - 96u : 0u);
        } else break;
      } else if (tot < KTOP) {
        uhi_ = f2u_desc(thr);
        if (attempt == 0) thr = 11.0f;
        else {
          uint32_t mid = ulo_ + (uhi_ - ulo_) / 2u;
          if (mid >= uhi_) mid = uhi_ - 1u;
          thr = u2f(mid);
        }
      } else {
        ulo_ = f2u_desc(thr);
        uint32_t mid = ulo_ + (uhi_ - ulo_) / 2u;
        if (mid <= ulo_) mid = ulo_ + 1u;
        thr = u2f(mid);
      }
    }
  }

  if (n == 0) { if (tid == 0) out[b] = 0.f; return; }

  // ---- top-k survivors (>= kth incl. ties) ----
  if (tid == 0) {
    int kpos = (n < KTOP) ? (n - 1) : (KTOP - 1);
    uint32_t kth = su[kpos];
    int ns = kpos + 1;
    while (ns < n && su[ns] == kth) ns++;
    s_nsurv = ns;
  }
  __syncthreads();
  const int nsurv = s_nsurv;
  const float s0 = u2f(su[0]);
  const uint32_t half_total = (uint32_t)((size_t)256 * V_CONST / 2);

  for (int r = tid; r < nsurv; r += NTHREADS) {
    float f = u2f(su[r]);
    eg[r] = expf(f - s0);
    gg[r] = gumbel_at((uint32_t)(b * V_CONST + sidx[r]), half_total);
  }
  __syncthreads();

  // ---- serial tail: top-p cutoff, Z, categorical (matches XLA order) ----
  if (tid == 0) {
    float zall = 0.f;
    for (int r = 0; r < nsurv; r++) zall += eg[r];
    float cum = 0.f;
    int rlast = 0;
    for (int r = 0; r < nsurv; r++) {
      cum += eg[r] / zall;
      if (r == 0 || cum <= 0.9f) rlast = r;
      else break;
    }
    float z2 = 0.f;
    for (int r = 0; r <= rlast; r++) z2 += eg[r];
    float best = -3.402823466e38f; int besti = V_CONST;
    for (int r = 0; r <= rlast; r++) {
      float sc = u2f(su[r]) + gg[r];
      int idx = sidx[r];
      if (sc > best || (sc == best && idx < besti)) { best = sc; besti = idx; }
    }
    out[b] = (float)besti;
    s_rlast = rlast; s_z2 = z2;
  }
  __syncthreads();
  const int rlast = s_rlast;
  const float z2 = s_z2;

  // ---- scatter kept probs (zero-fill drained at earlier barriers) ----
  for (int r = tid; r <= rlast; r += NTHREADS) {
    prow[sidx[r]] = eg[r] / z2;
  }
}

extern "C" void kernel_launch(void* const* d_in, const int* in_sizes, int n_in,
                              void* d_out, int out_size, void* d_ws, size_t ws_size,
                              hipStream_t stream) {
  const float* logits = (const float*)d_in[0];
  const int* generated = (const int*)d_in[1];
  float* out = (float*)d_out;
  const int B = in_sizes[0] / V_CONST;
  const int T = in_sizes[1] / B;
  hipLaunchKernelGGL(sample_kernel, dim3(B), dim3(NTHREADS), 0, stream,
                     logits, generated, out, B, T);
}